// Round 9
// baseline (220.996 us; speedup 1.0000x reference)
//
#include <hip/hip_runtime.h>
#include <hip/hip_bf16.h>

typedef __bf16 bf16;
typedef __bf16 bf16x8 __attribute__((ext_vector_type(8)));
typedef __bf16 bf16x4 __attribute__((ext_vector_type(4)));
typedef float  f32x4  __attribute__((ext_vector_type(4)));

#define GLD_LDS(g, l)                                                        \
  __builtin_amdgcn_global_load_lds(                                          \
      (const __attribute__((address_space(1))) void*)(g),                    \
      (__attribute__((address_space(3))) void*)(l), 16, 0, 0)

#define SB()    __builtin_amdgcn_s_barrier()
#define LG0()   asm volatile("s_waitcnt lgkmcnt(0)" ::: "memory")
#define WVM(n)  asm volatile("s_waitcnt vmcnt(" #n ")" ::: "memory")
#define PRIO1() __builtin_amdgcn_s_setprio(1)
#define PRIO0() __builtin_amdgcn_s_setprio(0)

// ---------------------------------------------------------------------------
// gemm8p: 256x256 tile, BK=64 split as 2 K-halves (kk=0/1, 32 cols each),
// 8 waves (2Mx4N, wave tile 128x64), 8 phases per 2 K-tiles.
// Phase p: [4-8 ds_read for THIS phase's MFMA] [2 gld_lds stage] [SB]
//          [lgkmcnt(0) — barrier wait overlaps own drain] [16 MFMA] [SB]
// MFMA order per tile: ph a: kk0·mg0, b: kk0·mg1, c: kk1·mg0, d: kk1·mg1.
// Staging (2 issues per phase, K-half granularity => consumed in staged
// order => COUNTED gates): ph1 A(T+1)k0 | ph2 B(T+1)k0 | ph3 A(T+1)k1 |
// ph4 B(T+1)k1 | ph5 A(T+2)k0 | ph6 B(T+2)k0 | ph7 A(T+2)k1 | ph8 B(T+2)k1.
// Gate vmcnt(4) at END of every even phase — always waits only on loads
// >=2 phases old; stage->first-read distance 3-4 phases (> HBM latency).
//   end-ph2 protects ph3 (T.k1, staged prev ph7/8); end-ph4 protects ph5
//   (T+1.k0, ph1/2); end-ph6 protects ph7 (T+1.k1, ph3/4); end-ph8 protects
//   next-ph1 (T+2.k0, ph5/6). Tail (T+2>=NT): ph6/ph8 gates -> vmcnt(0).
// Overwrite-safety: buf0 reads drain at ph4's LG0 (pre-barrier) -> ph5
// stages safe; buf1 at ph8's LG0 -> next ph1 stages safe.
// LDS 128K: A @0 = 2buf x 2kk x 16KB; B @65536 same. 64B rows; swizzle:
// slot s at row r holds k-chunk fq = s ^ g(r), g(r)=(r+(r>>2))&3 —
// <=2-way bank aliasing (free) for b128 reads; staging source pre-applies
// the same involution, LDS dest linear (rule #21 both-sides).
// EPI=0: bf16 store. EPI=1: fp32 + bias, nontemporal (protect L2/L3 inputs).
// C = A (MxK rm) * B^T (B NxK rm). M,N%256==0, K%128==0.
// ---------------------------------------------------------------------------
template <int EPI>
__global__ __launch_bounds__(512, 2)
void gemm8p(const bf16* __restrict__ A, const bf16* __restrict__ B,
            bf16* __restrict__ Cb, float* __restrict__ Cf,
            const float* __restrict__ bias_p, int M, int N, int K) {
  extern __shared__ bf16 lds[];
  const int tid  = threadIdx.x;
  const int lane = tid & 63, wave = tid >> 6;
  const int wm = wave >> 2, wn = wave & 3;       // 2 x 4 waves
  const int fr = lane & 15, fq = lane >> 4;
  const int gl = (fr + (fr >> 2)) & 3;           // read-side swizzle
  const int slotb = ((fq ^ gl) << 4);            // byte within 64B row

  // XCD-aware block swizzle (nwg divisible by 8)
  const int nwg = gridDim.x;
  const int bid = blockIdx.x;
  const int swz = (bid & 7) * (nwg >> 3) + (bid >> 3);
  const int gx  = N >> 8;
  const int row0 = (swz / gx) << 8, col0 = (swz % gx) << 8;

  // staging source: thread t writes LDS linear t*16B (row t>>2, slot t&3);
  // pre-swizzled global chunk = (t&3) ^ g(t>>2)
  const int gsrc  = ((tid >> 2) + (tid >> 4)) & 3;
  const int chunk = (tid & 3) ^ gsrc;
  const int srow  = tid >> 2;                    // 0..127 within issue block
  const bf16* Agl = A + (size_t)(row0 + srow) * K + chunk * 8;
  const bf16* Bgl = B + (size_t)(col0 + srow) * K + chunk * 8;

  // stage one K-half (kk) of tile t, operand base tb (elems: A=0,B=32768)
#define STGH(gl_, tb, t, kk)                                                 \
  do {                                                                       \
    const size_t _k = (size_t)(t) * 64 + (kk) * 32;                          \
    GLD_LDS((gl_) + _k,                                                      \
            lds + (tb) + ((t) & 1) * 16384 + (kk) * 8192 + wave * 512);      \
    GLD_LDS((gl_) + (size_t)128 * K + _k,                                    \
            lds + (tb) + ((t) & 1) * 16384 + (kk) * 8192 + 4096 + wave * 512);\
  } while (0)

  const char* ldsc = (const char*)lds;
  const char* Ab = ldsc + wm * 8192 + fr * 64 + slotb;          // +p*32K+kk*16K+mg*4K+m*1K
  const char* Bb = ldsc + 65536 + wn * 4096 + fr * 64 + slotb;  // +p*32K+kk*16K+n*1K

  f32x4  acc[8][4] = {};
  bf16x8 af[4], bg[4];

#define LDAQ(mg, kk, p)                                                      \
  do {                                                                       \
    _Pragma("unroll") for (int m_ = 0; m_ < 4; ++m_)                         \
      af[m_] = *(const bf16x8*)(Ab + (p) * 32768 + (kk) * 16384 +            \
                                (mg) * 4096 + m_ * 1024);                    \
  } while (0)

#define LDBQ(kk, p)                                                          \
  do {                                                                       \
    _Pragma("unroll") for (int n_ = 0; n_ < 4; ++n_)                         \
      bg[n_] = *(const bf16x8*)(Bb + (p) * 32768 + (kk) * 16384 + n_ * 1024);\
  } while (0)

#define MMQ(mg)                                                              \
  do {                                                                       \
    _Pragma("unroll") for (int m_ = 0; m_ < 4; ++m_)                         \
      _Pragma("unroll") for (int n_ = 0; n_ < 4; ++n_)                       \
        acc[(mg) * 4 + m_][n_] = __builtin_amdgcn_mfma_f32_16x16x32_bf16(    \
            af[m_], bg[n_], acc[(mg) * 4 + m_][n_], 0, 0, 0);                \
  } while (0)

  // prologue: tile 0 fully (8 issues), full drain
  STGH(Agl, 0, 0, 0); STGH(Bgl, 32768, 0, 0);
  STGH(Agl, 0, 0, 1); STGH(Bgl, 32768, 0, 1);
  WVM(0); SB();

  const int NT = K >> 6;                // K%128==0 => NT even
  for (int T = 0; T < NT; T += 2) {
    const bool s2 = (T + 2 < NT);
    // ===== tile T (buf0); stages -> tile T+1 (buf1) =====
    LDAQ(0, 0, 0); LDBQ(0, 0);          // ph1
    STGH(Agl, 0, T + 1, 0);
    SB(); LG0(); PRIO1(); MMQ(0); PRIO0(); SB();
    LDAQ(1, 0, 0);                      // ph2
    STGH(Bgl, 32768, T + 1, 0);
    SB(); LG0(); PRIO1(); MMQ(1); PRIO0(); WVM(4); SB();
    LDAQ(0, 1, 0); LDBQ(1, 0);          // ph3
    STGH(Agl, 0, T + 1, 1);
    SB(); LG0(); PRIO1(); MMQ(0); PRIO0(); SB();
    LDAQ(1, 1, 0);                      // ph4
    STGH(Bgl, 32768, T + 1, 1);
    SB(); LG0(); PRIO1(); MMQ(1); PRIO0(); WVM(4); SB();
    // ===== tile T+1 (buf1); stages -> tile T+2 (buf0) =====
    LDAQ(0, 0, 1); LDBQ(0, 1);          // ph5
    if (s2) STGH(Agl, 0, T + 2, 0);
    SB(); LG0(); PRIO1(); MMQ(0); PRIO0(); SB();
    LDAQ(1, 0, 1);                      // ph6
    if (s2) STGH(Bgl, 32768, T + 2, 0);
    SB(); LG0(); PRIO1(); MMQ(1); PRIO0();
    if (s2) { WVM(4); } else { WVM(0); }
    SB();
    LDAQ(0, 1, 1); LDBQ(1, 1);          // ph7
    if (s2) STGH(Agl, 0, T + 2, 1);
    SB(); LG0(); PRIO1(); MMQ(0); PRIO0(); SB();
    LDAQ(1, 1, 1);                      // ph8
    if (s2) STGH(Bgl, 32768, T + 2, 1);
    SB(); LG0(); PRIO1(); MMQ(1); PRIO0();
    if (s2) { WVM(4); } else { WVM(0); }
    SB();
  }

  // epilogue — C/D layout (verified): col = lane&15, row = (lane>>4)*4 + j
  const float bias = (EPI == 1) ? bias_p[0] : 0.0f;
#pragma unroll
  for (int m = 0; m < 8; ++m) {
#pragma unroll
    for (int n = 0; n < 4; ++n) {
      const int r = row0 + wm * 128 + m * 16 + fq * 4;
      const int c = col0 + wn * 64 + n * 16 + fr;
#pragma unroll
      for (int j = 0; j < 4; ++j) {
        if (EPI == 1)
          __builtin_nontemporal_store(acc[m][n][j] + bias,
                                      &Cf[(size_t)(r + j) * N + c]);
        else
          Cb[(size_t)(r + j) * N + c] = (bf16)acc[m][n][j];
      }
    }
  }
#undef STGH
#undef LDAQ
#undef LDBQ
#undef MMQ
}

// fp32 -> bf16 cast, 4 elems/thread
__global__ void cvt_f32_bf16(const float* __restrict__ in, bf16* __restrict__ out,
                             int n4) {
  int i = blockIdx.x * blockDim.x + threadIdx.x;
  if (i >= n4) return;
  const float4 v = ((const float4*)in)[i];
  bf16x4 o;
  o[0] = (bf16)v.x; o[1] = (bf16)v.y; o[2] = (bf16)v.z; o[3] = (bf16)v.w;
  ((bf16x4*)out)[i] = o;
}

// Wt[n][k] = (bf16) W[k][n], 1024x1024
__global__ void transpose_cvt_w(const float* __restrict__ W, bf16* __restrict__ Wt) {
  __shared__ float s[32][33];
  const int tx = threadIdx.x & 31;
  const int ty = threadIdx.x >> 5;
  const int n0 = blockIdx.x * 32;
  const int k0 = blockIdx.y * 32;
#pragma unroll
  for (int p = 0; p < 4; ++p)
    s[ty + p * 8][tx] = W[(size_t)(k0 + ty + p * 8) * 1024 + n0 + tx];
  __syncthreads();
#pragma unroll
  for (int p = 0; p < 4; ++p)
    Wt[(size_t)(n0 + ty + p * 8) * 1024 + k0 + tx] = (bf16)s[tx][ty + p * 8];
}

extern "C" void kernel_launch(void* const* d_in, const int* in_sizes, int n_in,
                              void* d_out, int out_size, void* d_ws, size_t ws_size,
                              hipStream_t stream) {
  const float* X = (const float*)d_in[0];   // (8192, 1024)
  const float* W = (const float*)d_in[1];   // (1024, 1024)
  const float* b = (const float*)d_in[2];   // (1,)
  float* out = (float*)d_out;               // (8192, 8192)

  const int Nn = 8192, D = 1024;
  char* ws = (char*)d_ws;
  bf16* Xb  = (bf16*)(ws);
  bf16* XWb = (bf16*)(ws + (size_t)16 * 1024 * 1024);
  bf16* Wt  = (bf16*)(ws + (size_t)32 * 1024 * 1024);

  cvt_f32_bf16<<<(Nn * D / 4 + 255) / 256, 256, 0, stream>>>(X, Xb, Nn * D / 4);
  transpose_cvt_w<<<dim3(D / 32, D / 32), 256, 0, stream>>>(W, Wt);
  // GEMM1: XW = Xb * Wt^T  (8192x1024, K=1024) -> bf16; 128 blocks, 1 round
  gemm8p<0><<<(Nn / 256) * (D / 256), 512, 131072, stream>>>(
      Xb, Wt, XWb, nullptr, nullptr, Nn, D, D);
  // GEMM2: out = XWb * Xb^T + b  (8192x8192, K=1024) fp32 nt-stores
  gemm8p<1><<<(Nn / 256) * (Nn / 256), 512, 131072, stream>>>(
      XWb, Xb, nullptr, out, b, Nn, Nn, D);
}

// Round 10
// 197.826 us; speedup vs baseline: 1.1171x; 1.1171x over previous
//
#include <hip/hip_runtime.h>
#include <hip/hip_bf16.h>

typedef __bf16 bf16;
typedef __bf16 bf16x8 __attribute__((ext_vector_type(8)));
typedef __bf16 bf16x4 __attribute__((ext_vector_type(4)));
typedef float  f32x4  __attribute__((ext_vector_type(4)));

#define GLD_LDS(g, l)                                                        \
  __builtin_amdgcn_global_load_lds(                                          \
      (const __attribute__((address_space(1))) void*)(g),                    \
      (__attribute__((address_space(3))) void*)(l), 16, 0, 0)

#define SB()    __builtin_amdgcn_s_barrier()
#define LG0()   asm volatile("s_waitcnt lgkmcnt(0)" ::: "memory")
#define WVM2()  asm volatile("s_waitcnt vmcnt(2)" ::: "memory")
#define WVM0()  asm volatile("s_waitcnt vmcnt(0)" ::: "memory")
#define PRIO1() __builtin_amdgcn_s_setprio(1)
#define PRIO0() __builtin_amdgcn_s_setprio(0)

// ---------------------------------------------------------------------------
// R5-verified 256x256 8-phase kernel (0 bank conflicts, absmax 0.5),
// + supertile block ordering for L3/L2 input residency.
// Block->tile mapping (M=N=8192 path): round = bid>>8 selects a 16x16
// output supertile (A+B panels 16MB -> L3-resident under write pressure);
// within it each XCD owns a 4x8 sub-region (A 2MB + B 4MB ~ its L2).
// Other shapes: bijective XCD-chunk fallback (nwg % 8 == 0).
// Schedule/ledger identical to R5 (verified): builtin barriers, lgkmcnt(0)
// at read-phases, counted vmcnt(2) at ph4/ph8, 1 half-tile staged/phase:
//  ph1 T+1.Ah1 | ph2 T+1.Bh0 | ph3 T+1.Bh1 | ph4 T+2.Ah0 +vmcnt(2)
//  ph5 T+2.Ah1 | ph6 T+2.Bh0 | ph7 T+2.Bh1 | ph8 T+3.Ah0 +vmcnt(2)
// LDS 128K: A dbuf @0, B dbuf @65536; XOR swizzle byte bits4-6 ^= row&7,
// staging pre-swizzles the global k-chunk (rule #21 both-sides).
// EPI=0: bf16 C. EPI=1: fp32 C + bias. C = A*B^T. M,N%256==0, K%128==0.
// ---------------------------------------------------------------------------
template <int EPI>
__global__ __launch_bounds__(512, 2)
void gemm256(const bf16* __restrict__ A, const bf16* __restrict__ B,
             bf16* __restrict__ Cb, float* __restrict__ Cf,
             const float* __restrict__ bias_p, int M, int N, int K) {
  extern __shared__ bf16 lds[];
  const int tid  = threadIdx.x;
  const int lane = tid & 63, wave = tid >> 6;
  const int wm = wave >> 2, wn = wave & 3;       // 2 x 4 waves
  const int fr = lane & 15, fq = lane >> 4;
  const int xm = (fr & 7) << 4;
  const int kx0 = (fq * 16) ^ xm;
  const int kx1 = (fq * 16 + 64) ^ xm;

  // ---- block -> output tile ----
  const int nwg = gridDim.x;
  const int bid = blockIdx.x;
  const int gx  = N >> 8;
  int tile_r, tile_c;
  if (gx == 32 && (M >> 8) == 32) {
    // supertile path: 4 rounds x (16x16 supertile); XCD-compact 4x8 regions
    const int round = bid >> 8, idx = bid & 255;
    const int xcd = idx & 7, pos = idx >> 3;        // pos 0..31
    tile_r = (round >> 1) * 16 + (xcd >> 1) * 4 + (pos >> 3);
    tile_c = (round & 1) * 16 + (xcd & 1) * 8 + (pos & 7);
  } else {
    const int swz = (bid & 7) * (nwg >> 3) + (bid >> 3);
    tile_r = swz / gx; tile_c = swz % gx;
  }
  const int row0 = tile_r << 8, col0 = tile_c << 8;

  // staging source (pre-swizzled k-chunk)
  const int srow = wave * 8 + (lane >> 3);
  const int scol = ((lane & 7) ^ (lane >> 3)) * 8;
  const bf16* Agl = A + (size_t)(row0 + srow) * K + scol;
  const bf16* Bgl = B + (size_t)(col0 + srow) * K + scol;

  // stage half-tile h of K-tile t; tb = 0 (A) or 32768 (B), elem offsets
#define STG(gl, tb, t, h)                                                    \
  do {                                                                       \
    const size_t _k = (size_t)(t) * 64;                                      \
    GLD_LDS((gl) + (size_t)((h) * 128) * K + _k,                             \
            lds + (tb) + ((t) & 1) * 16384 + (h) * 8192 + wave * 512);       \
    GLD_LDS((gl) + (size_t)((h) * 128 + 64) * K + _k,                        \
            lds + (tb) + ((t) & 1) * 16384 + (h) * 8192 + 4096 + wave * 512);\
  } while (0)

  const char* ldsc = (const char*)lds;
  const char* Ab0 = ldsc + wm * 16384 + fr * 128 + kx0;
  const char* Ab1 = ldsc + wm * 16384 + fr * 128 + kx1;
  const char* Bb0 = ldsc + 65536 + wn * 8192 + fr * 128 + kx0;
  const char* Bb1 = ldsc + 65536 + wn * 8192 + fr * 128 + kx1;

  f32x4  acc[8][4] = {};
  bf16x8 af[4][2];
  bf16x8 bg[4][2];

#define LDA(mg, p)                                                           \
  do {                                                                       \
    _Pragma("unroll") for (int m_ = 0; m_ < 4; ++m_) {                       \
      af[m_][0] = *(const bf16x8*)(Ab0 + (p) * 32768 + ((mg) * 4 + m_) * 2048);\
      af[m_][1] = *(const bf16x8*)(Ab1 + (p) * 32768 + ((mg) * 4 + m_) * 2048);\
    }                                                                        \
  } while (0)

#define LDB(np, p)                                                           \
  do {                                                                       \
    _Pragma("unroll") for (int n_ = 0; n_ < 2; ++n_) {                       \
      bg[(np) * 2 + n_][0] =                                                 \
          *(const bf16x8*)(Bb0 + (p) * 32768 + ((np) * 2 + n_) * 2048);      \
      bg[(np) * 2 + n_][1] =                                                 \
          *(const bf16x8*)(Bb1 + (p) * 32768 + ((np) * 2 + n_) * 2048);      \
    }                                                                        \
  } while (0)

#define MM(mg, np)                                                           \
  do {                                                                       \
    _Pragma("unroll") for (int kk_ = 0; kk_ < 2; ++kk_)                      \
      _Pragma("unroll") for (int m_ = 0; m_ < 4; ++m_)                       \
        _Pragma("unroll") for (int n_ = 0; n_ < 2; ++n_)                     \
          acc[(mg) * 4 + m_][(np) * 2 + n_] =                                \
              __builtin_amdgcn_mfma_f32_16x16x32_bf16(                       \
                  af[m_][kk_], bg[(np) * 2 + n_][kk_],                       \
                  acc[(mg) * 4 + m_][(np) * 2 + n_], 0, 0, 0);               \
  } while (0)

  // prologue: T0 (4 halves) + T1.Ah0 => 10 loads; keep newest 2 in flight
  STG(Agl, 0, 0, 0); STG(Agl, 0, 0, 1);
  STG(Bgl, 32768, 0, 0); STG(Bgl, 32768, 0, 1);
  STG(Agl, 0, 1, 0);
  WVM2(); SB();

  const int NT = K >> 6;
  for (int T = 0; T < NT; T += 2) {
    const bool s2 = (T + 2 < NT), s3 = (T + 3 < NT);
    // ph1
    LDA(0, 0); LDB(0, 0);
    STG(Agl, 0, T + 1, 1);
    SB(); LG0(); PRIO1(); MM(0, 0); PRIO0(); SB();
    // ph2
    LDB(1, 0);
    STG(Bgl, 32768, T + 1, 0);
    SB(); LG0(); PRIO1(); MM(0, 1); PRIO0(); SB();
    // ph3
    LDA(1, 0);
    STG(Bgl, 32768, T + 1, 1);
    SB(); LG0(); PRIO1(); MM(1, 0); PRIO0(); SB();
    // ph4 (no reads)
    if (s2) STG(Agl, 0, T + 2, 0);
    SB(); PRIO1(); MM(1, 1); PRIO0();
    if (s2) { WVM2(); } else { WVM0(); }
    SB();
    // ph5
    LDA(0, 1); LDB(0, 1);
    if (s2) STG(Agl, 0, T + 2, 1);
    SB(); LG0(); PRIO1(); MM(0, 0); PRIO0(); SB();
    // ph6
    LDB(1, 1);
    if (s2) STG(Bgl, 32768, T + 2, 0);
    SB(); LG0(); PRIO1(); MM(0, 1); PRIO0(); SB();
    // ph7
    LDA(1, 1);
    if (s2) STG(Bgl, 32768, T + 2, 1);
    SB(); LG0(); PRIO1(); MM(1, 0); PRIO0(); SB();
    // ph8 (no reads)
    if (s3) STG(Agl, 0, T + 3, 0);
    SB(); PRIO1(); MM(1, 1); PRIO0();
    if (s3) { WVM2(); } else { WVM0(); }
    SB();
  }

  // epilogue — C/D layout (verified): col = lane&15, row = (lane>>4)*4 + j
  const float bias = (EPI == 1) ? bias_p[0] : 0.0f;
#pragma unroll
  for (int m = 0; m < 8; ++m) {
#pragma unroll
    for (int n = 0; n < 4; ++n) {
      const int r = row0 + wm * 128 + m * 16 + fq * 4;
      const int c = col0 + wn * 64 + n * 16 + fr;
#pragma unroll
      for (int j = 0; j < 4; ++j) {
        if (EPI == 1)
          Cf[(size_t)(r + j) * N + c] = acc[m][n][j] + bias;
        else
          Cb[(size_t)(r + j) * N + c] = (bf16)acc[m][n][j];
      }
    }
  }
#undef STG
#undef LDA
#undef LDB
#undef MM
}

// fp32 -> bf16 cast, 4 elems/thread
__global__ void cvt_f32_bf16(const float* __restrict__ in, bf16* __restrict__ out,
                             int n4) {
  int i = blockIdx.x * blockDim.x + threadIdx.x;
  if (i >= n4) return;
  const float4 v = ((const float4*)in)[i];
  bf16x4 o;
  o[0] = (bf16)v.x; o[1] = (bf16)v.y; o[2] = (bf16)v.z; o[3] = (bf16)v.w;
  ((bf16x4*)out)[i] = o;
}

// Wt[n][k] = (bf16) W[k][n], 1024x1024
__global__ void transpose_cvt_w(const float* __restrict__ W, bf16* __restrict__ Wt) {
  __shared__ float s[32][33];
  const int tx = threadIdx.x & 31;
  const int ty = threadIdx.x >> 5;
  const int n0 = blockIdx.x * 32;
  const int k0 = blockIdx.y * 32;
#pragma unroll
  for (int p = 0; p < 4; ++p)
    s[ty + p * 8][tx] = W[(size_t)(k0 + ty + p * 8) * 1024 + n0 + tx];
  __syncthreads();
#pragma unroll
  for (int p = 0; p < 4; ++p)
    Wt[(size_t)(n0 + ty + p * 8) * 1024 + k0 + tx] = (bf16)s[tx][ty + p * 8];
}

extern "C" void kernel_launch(void* const* d_in, const int* in_sizes, int n_in,
                              void* d_out, int out_size, void* d_ws, size_t ws_size,
                              hipStream_t stream) {
  const float* X = (const float*)d_in[0];   // (8192, 1024)
  const float* W = (const float*)d_in[1];   // (1024, 1024)
  const float* b = (const float*)d_in[2];   // (1,)
  float* out = (float*)d_out;               // (8192, 8192)

  const int Nn = 8192, D = 1024;
  char* ws = (char*)d_ws;
  bf16* Xb  = (bf16*)(ws);
  bf16* XWb = (bf16*)(ws + (size_t)16 * 1024 * 1024);
  bf16* Wt  = (bf16*)(ws + (size_t)32 * 1024 * 1024);

  cvt_f32_bf16<<<(Nn * D / 4 + 255) / 256, 256, 0, stream>>>(X, Xb, Nn * D / 4);
  transpose_cvt_w<<<dim3(D / 32, D / 32), 256, 0, stream>>>(W, Wt);
  // GEMM1: XW = Xb * Wt^T  (8192x1024, K=1024) -> bf16; 128 blocks, 1 round
  gemm256<0><<<(Nn / 256) * (D / 256), 512, 131072, stream>>>(
      Xb, Wt, XWb, nullptr, nullptr, Nn, D, D);
  // GEMM2: out = XWb * Xb^T + b  (8192x8192, K=1024) fp32
  gemm256<1><<<(Nn / 256) * (Nn / 256), 512, 131072, stream>>>(
      XWb, Xb, nullptr, out, b, Nn, Nn, D);
}

// Round 11
// 195.035 us; speedup vs baseline: 1.1331x; 1.0143x over previous
//
#include <hip/hip_runtime.h>
#include <hip/hip_bf16.h>

typedef __bf16 bf16;
typedef __bf16 bf16x8 __attribute__((ext_vector_type(8)));
typedef __bf16 bf16x4 __attribute__((ext_vector_type(4)));
typedef float  f32x4  __attribute__((ext_vector_type(4)));

#define GLD_LDS(g, l)                                                        \
  __builtin_amdgcn_global_load_lds(                                          \
      (const __attribute__((address_space(1))) void*)(g),                    \
      (__attribute__((address_space(3))) void*)(l), 16, 0, 0)

#define SB()    __builtin_amdgcn_s_barrier()
#define LG0()   asm volatile("s_waitcnt lgkmcnt(0)" ::: "memory")
#define WVM2()  asm volatile("s_waitcnt vmcnt(2)" ::: "memory")
#define WVM0()  asm volatile("s_waitcnt vmcnt(0)" ::: "memory")
#define PRIO1() __builtin_amdgcn_s_setprio(1)
#define PRIO0() __builtin_amdgcn_s_setprio(0)

// ---------------------------------------------------------------------------
// PERSISTENT R5-verified 256x256 8-phase kernel. Each block computes
// nTiles/nwg output tiles in-kernel (GEMM2: 4; GEMM1: 1), eliminating 3
// round-retire/relaunch/windup cycles (the measured ~18us/round overhead:
// per-round prologue drain + epilogue store drain before endpgm + dispatch
// gap). Tile mapping per iteration == R10's per-round mapping (supertile
// 16x16 with XCD-compact 4x8 regions for the 32x32 grid; XCD-chunk
// otherwise) -> identical L3/L2 locality (FETCH stays ~98MB).
// Junction: epilogue stores -> next prologue stages -> WVM(2) (counts
// pending stores too: conservative => safe) -> SB.
// K-loop/ledger/swizzle identical to R5/R10 (verified: 0 conflicts,
// absmax 0.5): builtin barriers, lgkmcnt(0) at read-phases, counted
// vmcnt(2) at ph4/ph8, 1 half-tile staged per phase.
// LDS 128K: A dbuf @0, B dbuf @65536; XOR swizzle byte bits4-6 ^= row&7,
// staging pre-swizzles the global k-chunk (rule #21 both-sides).
// EPI=0: bf16 C. EPI=1: fp32 C + bias. C = A*B^T. M,N%256==0, K%128==0.
// ---------------------------------------------------------------------------
template <int EPI>
__global__ __launch_bounds__(512, 2)
void gemm256(const bf16* __restrict__ A, const bf16* __restrict__ B,
             bf16* __restrict__ Cb, float* __restrict__ Cf,
             const float* __restrict__ bias_p, int M, int N, int K) {
  extern __shared__ bf16 lds[];
  const int tid  = threadIdx.x;
  const int lane = tid & 63, wave = tid >> 6;
  const int wm = wave >> 2, wn = wave & 3;       // 2 x 4 waves
  const int fr = lane & 15, fq = lane >> 4;
  const int xm = (fr & 7) << 4;
  const int kx0 = (fq * 16) ^ xm;
  const int kx1 = (fq * 16 + 64) ^ xm;

  const int nwg = gridDim.x;
  const int bid = blockIdx.x;
  const int gx  = N >> 8;
  const int nTiles = (M >> 8) * gx;
  const int rounds = nTiles / nwg;

  // lane-constant pieces of staging/read addressing
  const int srow = wave * 8 + (lane >> 3);
  const int scol = ((lane & 7) ^ (lane >> 3)) * 8;
  const char* ldsc = (const char*)lds;
  const char* Ab0 = ldsc + wm * 16384 + fr * 128 + kx0;
  const char* Ab1 = ldsc + wm * 16384 + fr * 128 + kx1;
  const char* Bb0 = ldsc + 65536 + wn * 8192 + fr * 128 + kx0;
  const char* Bb1 = ldsc + 65536 + wn * 8192 + fr * 128 + kx1;
  const float bias = (EPI == 1) ? bias_p[0] : 0.0f;

#define STG(gl, tb, t, h)                                                    \
  do {                                                                       \
    const size_t _k = (size_t)(t) * 64;                                      \
    GLD_LDS((gl) + (size_t)((h) * 128) * K + _k,                             \
            lds + (tb) + ((t) & 1) * 16384 + (h) * 8192 + wave * 512);       \
    GLD_LDS((gl) + (size_t)((h) * 128 + 64) * K + _k,                        \
            lds + (tb) + ((t) & 1) * 16384 + (h) * 8192 + 4096 + wave * 512);\
  } while (0)

#define LDA(mg, p)                                                           \
  do {                                                                       \
    _Pragma("unroll") for (int m_ = 0; m_ < 4; ++m_) {                       \
      af[m_][0] = *(const bf16x8*)(Ab0 + (p) * 32768 + ((mg) * 4 + m_) * 2048);\
      af[m_][1] = *(const bf16x8*)(Ab1 + (p) * 32768 + ((mg) * 4 + m_) * 2048);\
    }                                                                        \
  } while (0)

#define LDB(np, p)                                                           \
  do {                                                                       \
    _Pragma("unroll") for (int n_ = 0; n_ < 2; ++n_) {                       \
      bg[(np) * 2 + n_][0] =                                                 \
          *(const bf16x8*)(Bb0 + (p) * 32768 + ((np) * 2 + n_) * 2048);      \
      bg[(np) * 2 + n_][1] =                                                 \
          *(const bf16x8*)(Bb1 + (p) * 32768 + ((np) * 2 + n_) * 2048);      \
    }                                                                        \
  } while (0)

#define MM(mg, np)                                                           \
  do {                                                                       \
    _Pragma("unroll") for (int kk_ = 0; kk_ < 2; ++kk_)                      \
      _Pragma("unroll") for (int m_ = 0; m_ < 4; ++m_)                       \
        _Pragma("unroll") for (int n_ = 0; n_ < 2; ++n_)                     \
          acc[(mg) * 4 + m_][(np) * 2 + n_] =                                \
              __builtin_amdgcn_mfma_f32_16x16x32_bf16(                       \
                  af[m_][kk_], bg[(np) * 2 + n_][kk_],                       \
                  acc[(mg) * 4 + m_][(np) * 2 + n_], 0, 0, 0);               \
  } while (0)

  for (int rd = 0; rd < rounds; ++rd) {
    // ---- tile mapping (== R10 round rd) ----
    int tile_r, tile_c;
    if (gx == 32 && (M >> 8) == 32 && nwg == 256) {
      const int xcd = bid & 7, pos = bid >> 3;
      tile_r = (rd >> 1) * 16 + (xcd >> 1) * 4 + (pos >> 3);
      tile_c = (rd & 1) * 16 + (xcd & 1) * 8 + (pos & 7);
    } else {
      const int li = rd * nwg + bid;
      const int swz = (li & 7) * (nTiles >> 3) + (li >> 3);
      tile_r = swz / gx; tile_c = swz % gx;
    }
    const int row0 = tile_r << 8, col0 = tile_c << 8;

    const bf16* Agl = A + (size_t)(row0 + srow) * K + scol;
    const bf16* Bgl = B + (size_t)(col0 + srow) * K + scol;

    f32x4  acc[8][4] = {};
    bf16x8 af[4][2];
    bf16x8 bg[4][2];

    // prologue: T0 (4 halves) + T1.Ah0 => 10 loads; keep newest 2 in flight.
    // (rd>0: pending epilogue stores also count in vmcnt -> WVM2 drains them
    // too; conservative = safe.)
    STG(Agl, 0, 0, 0); STG(Agl, 0, 0, 1);
    STG(Bgl, 32768, 0, 0); STG(Bgl, 32768, 0, 1);
    STG(Agl, 0, 1, 0);
    WVM2(); SB();

    const int NT = K >> 6;
    for (int T = 0; T < NT; T += 2) {
      const bool s2 = (T + 2 < NT), s3 = (T + 3 < NT);
      // ph1
      LDA(0, 0); LDB(0, 0);
      STG(Agl, 0, T + 1, 1);
      SB(); LG0(); PRIO1(); MM(0, 0); PRIO0(); SB();
      // ph2
      LDB(1, 0);
      STG(Bgl, 32768, T + 1, 0);
      SB(); LG0(); PRIO1(); MM(0, 1); PRIO0(); SB();
      // ph3
      LDA(1, 0);
      STG(Bgl, 32768, T + 1, 1);
      SB(); LG0(); PRIO1(); MM(1, 0); PRIO0(); SB();
      // ph4 (no reads)
      if (s2) STG(Agl, 0, T + 2, 0);
      SB(); PRIO1(); MM(1, 1); PRIO0();
      if (s2) { WVM2(); } else { WVM0(); }
      SB();
      // ph5
      LDA(0, 1); LDB(0, 1);
      if (s2) STG(Agl, 0, T + 2, 1);
      SB(); LG0(); PRIO1(); MM(0, 0); PRIO0(); SB();
      // ph6
      LDB(1, 1);
      if (s2) STG(Bgl, 32768, T + 2, 0);
      SB(); LG0(); PRIO1(); MM(0, 1); PRIO0(); SB();
      // ph7
      LDA(1, 1);
      if (s2) STG(Bgl, 32768, T + 2, 1);
      SB(); LG0(); PRIO1(); MM(1, 0); PRIO0(); SB();
      // ph8 (no reads)
      if (s3) STG(Agl, 0, T + 3, 0);
      SB(); PRIO1(); MM(1, 1); PRIO0();
      if (s3) { WVM2(); } else { WVM0(); }
      SB();
    }

    // epilogue — C/D layout (verified): col = lane&15, row = (lane>>4)*4 + j
#pragma unroll
    for (int m = 0; m < 8; ++m) {
#pragma unroll
      for (int n = 0; n < 4; ++n) {
        const int r = row0 + wm * 128 + m * 16 + fq * 4;
        const int c = col0 + wn * 64 + n * 16 + fr;
#pragma unroll
        for (int j = 0; j < 4; ++j) {
          if (EPI == 1)
            Cf[(size_t)(r + j) * N + c] = acc[m][n][j] + bias;
          else
            Cb[(size_t)(r + j) * N + c] = (bf16)acc[m][n][j];
        }
      }
    }
    // stores drain asynchronously; next iteration's prologue overlaps them.
  }
#undef STG
#undef LDA
#undef LDB
#undef MM
}

// fp32 -> bf16 cast, 4 elems/thread
__global__ void cvt_f32_bf16(const float* __restrict__ in, bf16* __restrict__ out,
                             int n4) {
  int i = blockIdx.x * blockDim.x + threadIdx.x;
  if (i >= n4) return;
  const float4 v = ((const float4*)in)[i];
  bf16x4 o;
  o[0] = (bf16)v.x; o[1] = (bf16)v.y; o[2] = (bf16)v.z; o[3] = (bf16)v.w;
  ((bf16x4*)out)[i] = o;
}

// Wt[n][k] = (bf16) W[k][n], 1024x1024
__global__ void transpose_cvt_w(const float* __restrict__ W, bf16* __restrict__ Wt) {
  __shared__ float s[32][33];
  const int tx = threadIdx.x & 31;
  const int ty = threadIdx.x >> 5;
  const int n0 = blockIdx.x * 32;
  const int k0 = blockIdx.y * 32;
#pragma unroll
  for (int p = 0; p < 4; ++p)
    s[ty + p * 8][tx] = W[(size_t)(k0 + ty + p * 8) * 1024 + n0 + tx];
  __syncthreads();
#pragma unroll
  for (int p = 0; p < 4; ++p)
    Wt[(size_t)(n0 + ty + p * 8) * 1024 + k0 + tx] = (bf16)s[tx][ty + p * 8];
}

extern "C" void kernel_launch(void* const* d_in, const int* in_sizes, int n_in,
                              void* d_out, int out_size, void* d_ws, size_t ws_size,
                              hipStream_t stream) {
  const float* X = (const float*)d_in[0];   // (8192, 1024)
  const float* W = (const float*)d_in[1];   // (1024, 1024)
  const float* b = (const float*)d_in[2];   // (1,)
  float* out = (float*)d_out;               // (8192, 8192)

  const int Nn = 8192, D = 1024;
  char* ws = (char*)d_ws;
  bf16* Xb  = (bf16*)(ws);
  bf16* XWb = (bf16*)(ws + (size_t)16 * 1024 * 1024);
  bf16* Wt  = (bf16*)(ws + (size_t)32 * 1024 * 1024);

  cvt_f32_bf16<<<(Nn * D / 4 + 255) / 256, 256, 0, stream>>>(X, Xb, Nn * D / 4);
  transpose_cvt_w<<<dim3(D / 32, D / 32), 256, 0, stream>>>(W, Wt);
  // GEMM1: XW = Xb * Wt^T  (8192x1024, K=1024) -> bf16; 128 blocks, 1 round
  gemm256<0><<<(Nn / 256) * (D / 256), 512, 131072, stream>>>(
      Xb, Wt, XWb, nullptr, nullptr, Nn, D, D);
  // GEMM2: out = XWb * Xb^T + b  (8192x8192) fp32; 256 persistent blocks x 4
  gemm256<1><<<256, 512, 131072, stream>>>(
      XWb, Xb, nullptr, out, b, Nn, Nn, D);
}

// Round 12
// 189.823 us; speedup vs baseline: 1.1642x; 1.0275x over previous
//
#include <hip/hip_runtime.h>
#include <hip/hip_bf16.h>

typedef __bf16 bf16;
typedef __bf16 bf16x8 __attribute__((ext_vector_type(8)));
typedef __bf16 bf16x4 __attribute__((ext_vector_type(4)));
typedef float  f32x4  __attribute__((ext_vector_type(4)));

#define GLD_LDS(g, l)                                                        \
  __builtin_amdgcn_global_load_lds(                                          \
      (const __attribute__((address_space(1))) void*)(g),                    \
      (__attribute__((address_space(3))) void*)(l), 16, 0, 0)

#define SB()    __builtin_amdgcn_s_barrier()
#define WVM(n)  asm volatile("s_waitcnt vmcnt(" #n ")" ::: "memory")
#define PRIO1() __builtin_amdgcn_s_setprio(1)
#define PRIO0() __builtin_amdgcn_s_setprio(0)

// ---------------------------------------------------------------------------
// R5-ledger 256x256 8-phase kernel, low-overhead edition:
//  - K (=1024) and N are compile-time (KP/NP): all stage/read addresses are
//    running-pointer + literal; no runtime muls in the loop.
//  - NO blanket lgkmcnt(0): MFMA operand waits are compiler-inserted partial
//    lgkm waits, so the LDS drain retires UNDER the MFMA burst. Ledger
//    safety: every read's consuming MFMA precedes the phase's closing
//    barrier, so reads complete before any wave passes that barrier; the
//    next writer of that LDS region issues >=1 barrier later.  Counted
//    vmcnt(2) gates at ph4/ph8 (asm+memory, unchanged R5 semantics).
//  - Reads issued kk0-first so the first MFMA's operands drain earliest.
//  - Persistent blocks; next tile's prologue (T0 all + T1.Ah0 = 10 loads)
//    is staged in the LAST iteration's stage slots (identical ledger
//    positions), so tile junction = [epilogue stores][WVM(63): drains the
//    2 pending T1.Ah0 stage loads + ~half the stores][SB] -> no separate
//    prologue and half the store drain hidden.
// Staging order/ledger (per 2 K-tiles, verified R5): ph1 T+1.Ah1 |
//  ph2 T+1.Bh0 | ph3 T+1.Bh1 | ph4 T+2.Ah0 +WVM2 | ph5 T+2.Ah1 |
//  ph6 T+2.Bh0 | ph7 T+2.Bh1 | ph8 T+3.Ah0 +WVM2.
// LDS 128K: A dbuf @0 (2x32KB), B dbuf @65536; XOR swizzle byte bits4-6 ^=
//  row&7 on reads; staging pre-swizzles the global k-chunk (rule #21).
// EPI=0: bf16 C (N=1024). EPI=1: fp32 C + bias (N=8192). C = A*B^T.
// ---------------------------------------------------------------------------
template <int EPI, int NP>
__global__ __launch_bounds__(512, 2)
void gemm256(const bf16* __restrict__ A, const bf16* __restrict__ B,
             bf16* __restrict__ Cb, float* __restrict__ Cf,
             const float* __restrict__ bias_p, int M) {
  constexpr int KP = 1024;
  constexpr int NT = KP / 64;            // 16 K-tiles
  extern __shared__ bf16 lds[];
  const int tid  = threadIdx.x;
  const int lane = tid & 63, wave = tid >> 6;
  const int wm = wave >> 2, wn = wave & 3;       // 2 x 4 waves
  const int fr = lane & 15, fq = lane >> 4;
  const int xm = (fr & 7) << 4;
  const int kx0 = (fq * 16) ^ xm;
  const int kx1 = (fq * 16 + 64) ^ xm;

  const int nwg = gridDim.x;
  const int bid = blockIdx.x;
  constexpr int gx = NP >> 8;
  const int nTiles = (M >> 8) * gx;
  const int rounds = nTiles / nwg;

  // staging source lane geometry (pre-swizzled k-chunk)
  const int srow = wave * 8 + (lane >> 3);
  const int scol = ((lane & 7) ^ (lane >> 3)) * 8;

  // LDS bases
  bf16* ldsA = lds + wave * 512;
  bf16* ldsB = lds + 32768 + wave * 512;
  const char* ldsc = (const char*)lds;
  const char* Ab0 = ldsc + wm * 16384 + fr * 128 + kx0;
  const char* Ab1 = ldsc + wm * 16384 + fr * 128 + kx1;
  const char* Bb0 = ldsc + 65536 + wn * 8192 + fr * 128 + kx0;
  const char* Bb1 = ldsc + 65536 + wn * 8192 + fr * 128 + kx1;

  const float bias = (EPI == 1) ? bias_p[0] : 0.0f;

#define STG2(p0, p1, trel, base, off)                                        \
  do {                                                                       \
    GLD_LDS((p0) + (trel) * 64, (base) + (off));                             \
    GLD_LDS((p1) + (trel) * 64, (base) + (off) + 4096);                      \
  } while (0)

#define LDA4(mg, kk, p)                                                      \
  do {                                                                       \
    _Pragma("unroll") for (int m_ = 0; m_ < 4; ++m_)                         \
      af[m_][kk] = *(const bf16x8*)(Ab##kk + (p) * 32768 +                   \
                                    ((mg) * 4 + m_) * 2048);                 \
  } while (0)

#define LDB2(np, kk, p)                                                      \
  do {                                                                       \
    _Pragma("unroll") for (int n_ = 0; n_ < 2; ++n_)                         \
      bg[(np) * 2 + n_][kk] = *(const bf16x8*)(Bb##kk + (p) * 32768 +        \
                                               ((np) * 2 + n_) * 2048);      \
  } while (0)

#define MM(mg, np)                                                           \
  do {                                                                       \
    _Pragma("unroll") for (int kk_ = 0; kk_ < 2; ++kk_)                      \
      _Pragma("unroll") for (int m_ = 0; m_ < 4; ++m_)                       \
        _Pragma("unroll") for (int n_ = 0; n_ < 2; ++n_)                     \
          acc[(mg) * 4 + m_][(np) * 2 + n_] =                                \
              __builtin_amdgcn_mfma_f32_16x16x32_bf16(                       \
                  af[m_][kk_], bg[(np) * 2 + n_][kk_],                       \
                  acc[(mg) * 4 + m_][(np) * 2 + n_], 0, 0, 0);               \
  } while (0)

#define PHASE(RDS, STAGE, MMC, GATE)                                         \
  do { RDS; STAGE; SB(); PRIO1(); MMC; PRIO0(); GATE; SB(); } while (0)

#define RD1 do { LDB2(0,0,0); LDA4(0,0,0); LDB2(0,1,0); LDA4(0,1,0); } while(0)
#define RD2 do { LDB2(1,0,0); LDB2(1,1,0); } while(0)
#define RD3 do { LDA4(1,0,0); LDA4(1,1,0); } while(0)
#define RD5 do { LDB2(0,0,1); LDA4(0,0,1); LDB2(0,1,1); LDA4(0,1,1); } while(0)
#define RD6 do { LDB2(1,0,1); LDB2(1,1,1); } while(0)
#define RD7 do { LDA4(1,0,1); LDA4(1,1,1); } while(0)

  // ---- tile mapping ----
  auto mapTile = [&](int rd, int& tr, int& tc) {
    if (NP == 8192 && nwg == 256 && (M >> 8) == 32) {
      const int xcd = bid & 7, pos = bid >> 3;
      tr = (rd >> 1) * 16 + (xcd >> 1) * 4 + (pos >> 3);
      tc = (rd & 1) * 16 + (xcd & 1) * 8 + (pos & 7);
    } else {
      const int li = rd * nwg + bid;
      const int swz = (li & 7) * (nTiles >> 3) + (li >> 3);
      tr = li < nTiles ? swz / gx : 0; tc = li < nTiles ? swz % gx : 0;
    }
  };

  int tr, tc;
  mapTile(0, tr, tc);
  int row0 = tr << 8, col0 = tc << 8;

  const bf16* a0 = A + (size_t)(row0 + srow) * KP + scol;
  const bf16* a1 = a0 + (size_t)64 * KP;
  const bf16* a2 = a0 + (size_t)128 * KP;
  const bf16* a3 = a0 + (size_t)192 * KP;
  const bf16* b0 = B + (size_t)(col0 + srow) * KP + scol;
  const bf16* b1 = b0 + (size_t)64 * KP;
  const bf16* b2 = b0 + (size_t)128 * KP;
  const bf16* b3 = b0 + (size_t)192 * KP;

  // prologue: T0 (4 halves) + T1.Ah0
  STG2(a0, a1, 0, ldsA, 0);
  STG2(a2, a3, 0, ldsA, 8192);
  STG2(b0, b1, 0, ldsB, 0);
  STG2(b2, b3, 0, ldsB, 8192);
  STG2(a0, a1, 1, ldsA, 16384);

  for (int rd = 0; rd < rounds; ++rd) {
    if (rd == 0) { WVM(2); } else { WVM(63); }
    SB();

    f32x4  acc[8][4] = {};
    bf16x8 af[4][2];
    bf16x8 bg[4][2];

#pragma unroll 1
    for (int it = 0; it < NT / 2 - 1; ++it) {
      PHASE(RD1, STG2(a2, a3, 1, ldsA, 24576), MM(0, 0), );
      PHASE(RD2, STG2(b0, b1, 1, ldsB, 16384), MM(0, 1), );
      PHASE(RD3, STG2(b2, b3, 1, ldsB, 24576), MM(1, 0), );
      PHASE(   , STG2(a0, a1, 2, ldsA, 0),     MM(1, 1), WVM(2));
      PHASE(RD5, STG2(a2, a3, 2, ldsA, 8192),  MM(0, 0), );
      PHASE(RD6, STG2(b0, b1, 2, ldsB, 0),     MM(0, 1), );
      PHASE(RD7, STG2(b2, b3, 2, ldsB, 8192),  MM(1, 0), );
      PHASE(   , STG2(a0, a1, 3, ldsA, 16384), MM(1, 1), WVM(2));
      a0 += 128; a1 += 128; a2 += 128; a3 += 128;
      b0 += 128; b1 += 128; b2 += 128; b3 += 128;
    }

    // peeled last iteration: stage NEXT tile's prologue in ph4-ph8 slots
    const bool hn = (rd + 1 < rounds);
    int ntr, ntc;
    mapTile(rd + 1, ntr, ntc);
    const int nrow0 = ntr << 8, ncol0 = ntc << 8;
    const bf16* na0 = A + (size_t)(nrow0 + srow) * KP + scol;
    const bf16* na1 = na0 + (size_t)64 * KP;
    const bf16* na2 = na0 + (size_t)128 * KP;
    const bf16* na3 = na0 + (size_t)192 * KP;
    const bf16* nb0 = B + (size_t)(ncol0 + srow) * KP + scol;
    const bf16* nb1 = nb0 + (size_t)64 * KP;
    const bf16* nb2 = nb0 + (size_t)128 * KP;
    const bf16* nb3 = nb0 + (size_t)192 * KP;

    PHASE(RD1, STG2(a2, a3, 1, ldsA, 24576), MM(0, 0), );
    PHASE(RD2, STG2(b0, b1, 1, ldsB, 16384), MM(0, 1), );
    PHASE(RD3, STG2(b2, b3, 1, ldsB, 24576), MM(1, 0), );
    PHASE(   , if (hn) { STG2(na0, na1, 0, ldsA, 0); },    MM(1, 1),
           if (hn) { WVM(2); } else { WVM(0); });
    PHASE(RD5, if (hn) { STG2(na2, na3, 0, ldsA, 8192); }, MM(0, 0), );
    PHASE(RD6, if (hn) { STG2(nb0, nb1, 0, ldsB, 0); },    MM(0, 1), );
    PHASE(RD7, if (hn) { STG2(nb2, nb3, 0, ldsB, 8192); }, MM(1, 0), );
    PHASE(   , if (hn) { STG2(na0, na1, 1, ldsA, 16384); }, MM(1, 1),
           if (hn) { WVM(2); } else { WVM(0); });

    // epilogue — C/D layout (verified): col = lane&15, row = (lane>>4)*4 + j
#pragma unroll
    for (int m = 0; m < 8; ++m) {
#pragma unroll
      for (int n = 0; n < 4; ++n) {
        const int r = row0 + wm * 128 + m * 16 + fq * 4;
        const int c = col0 + wn * 64 + n * 16 + fr;
#pragma unroll
        for (int j = 0; j < 4; ++j) {
          if (EPI == 1)
            Cf[(size_t)(r + j) * NP + c] = acc[m][n][j] + bias;
          else
            Cb[(size_t)(r + j) * NP + c] = (bf16)acc[m][n][j];
        }
      }
    }

    // advance to next tile
    a0 = na0; a1 = na1; a2 = na2; a3 = na3;
    b0 = nb0; b1 = nb1; b2 = nb2; b3 = nb3;
    row0 = nrow0; col0 = ncol0;
  }
#undef STG2
#undef LDA4
#undef LDB2
#undef MM
#undef PHASE
#undef RD1
#undef RD2
#undef RD3
#undef RD5
#undef RD6
#undef RD7
}

// fp32 -> bf16 cast, 4 elems/thread
__global__ void cvt_f32_bf16(const float* __restrict__ in, bf16* __restrict__ out,
                             int n4) {
  int i = blockIdx.x * blockDim.x + threadIdx.x;
  if (i >= n4) return;
  const float4 v = ((const float4*)in)[i];
  bf16x4 o;
  o[0] = (bf16)v.x; o[1] = (bf16)v.y; o[2] = (bf16)v.z; o[3] = (bf16)v.w;
  ((bf16x4*)out)[i] = o;
}

// Wt[n][k] = (bf16) W[k][n], 1024x1024
__global__ void transpose_cvt_w(const float* __restrict__ W, bf16* __restrict__ Wt) {
  __shared__ float s[32][33];
  const int tx = threadIdx.x & 31;
  const int ty = threadIdx.x >> 5;
  const int n0 = blockIdx.x * 32;
  const int k0 = blockIdx.y * 32;
#pragma unroll
  for (int p = 0; p < 4; ++p)
    s[ty + p * 8][tx] = W[(size_t)(k0 + ty + p * 8) * 1024 + n0 + tx];
  __syncthreads();
#pragma unroll
  for (int p = 0; p < 4; ++p)
    Wt[(size_t)(n0 + ty + p * 8) * 1024 + k0 + tx] = (bf16)s[tx][ty + p * 8];
}

extern "C" void kernel_launch(void* const* d_in, const int* in_sizes, int n_in,
                              void* d_out, int out_size, void* d_ws, size_t ws_size,
                              hipStream_t stream) {
  const float* X = (const float*)d_in[0];   // (8192, 1024)
  const float* W = (const float*)d_in[1];   // (1024, 1024)
  const float* b = (const float*)d_in[2];   // (1,)
  float* out = (float*)d_out;               // (8192, 8192)

  const int Nn = 8192, D = 1024;
  char* ws = (char*)d_ws;
  bf16* Xb  = (bf16*)(ws);
  bf16* XWb = (bf16*)(ws + (size_t)16 * 1024 * 1024);
  bf16* Wt  = (bf16*)(ws + (size_t)32 * 1024 * 1024);

  cvt_f32_bf16<<<(Nn * D / 4 + 255) / 256, 256, 0, stream>>>(X, Xb, Nn * D / 4);
  transpose_cvt_w<<<dim3(D / 32, D / 32), 256, 0, stream>>>(W, Wt);
  // GEMM1: XW = Xb * Wt^T  (8192x1024, K=1024) -> bf16; 128 blocks, 1 round
  gemm256<0, 1024><<<128, 512, 131072, stream>>>(Xb, Wt, XWb, nullptr, nullptr,
                                                 Nn);
  // GEMM2: out = XWb * Xb^T + b  (8192x8192) fp32; 256 persistent blocks x 4
  gemm256<1, 8192><<<256, 512, 131072, stream>>>(XWb, Xb, nullptr, out, b, Nn);
}